// Round 1
// baseline (379.889 us; speedup 1.0000x reference)
//
#include <hip/hip_runtime.h>
#include <math.h>

#define LMAX   5
#define MUL    128
#define NCH    4
#define NRAD   64
#define RBETA  180
#define RALPHA 359
#define NGRAPH 16
#define SH_DIM 36
#define EMB_DIM 4608
#define NIRR   768

#define GRID_BA (RBETA * RALPHA)          // 64620
#define NW21    21                        // (LMAX+1)(LMAX+2)/2 packed (l,m) weights

// out layout (floats): [0] coeffs 147456 | [1] pos 66170880 | [2] ang 1033920 | [3] rad 1024
#define OUT0_OFF 0
#define OUT1_OFF 147456
#define OUT2_OFF (147456 + 66170880)
#define OUT3_OFF (147456 + 66170880 + 1033920)

// ws layout (bytes):
//   float tab[180*21]  @ 0      (15120 B, padded to 15360)
//   float ang[16][144] @ 15360  (9216 B)
//   float rad[16][64]  @ 24576  (4096 B)
#define WS_TAB_OFF 0
#define WS_ANG_OFF 15360
#define WS_RAD_OFF 24576

// ---------------------------------------------------------------------------
// Host-side precompute (grid is static): Gauss-Legendre nodes of P_180 via
// Newton in fp64, then the per-beta packed SH weights
//   tab[beta][l(l+1)/2+m] = (m==0 ? 1 : sqrt2) * N_lm * P_lm(y_beta)
// Replaces the serial k_nodes kernel AND the per-block fp64 Legendre section.
static float g_tab[RBETA * NW21];
static bool  g_tab_ready = false;

static void host_init_tab() {
    if (g_tab_ready) return;
    const double PI = 3.14159265358979323846;
    const double FOURPI = 12.566370614359172;
    for (int i = 0; i < RBETA; ++i) {
        // ascending node i: negated Chebyshev-like initial guess
        double x = -cos(PI * (i + 0.75) / (RBETA + 0.5));
        for (int it = 0; it < 40; ++it) {
            double p0 = 1.0, p1 = x;
            for (int k = 1; k < RBETA; ++k) {
                double p2 = ((2.0 * k + 1.0) * x * p1 - (double)k * p0) / (double)(k + 1);
                p0 = p1; p1 = p2;
            }
            double dp = RBETA * (x * p1 - p0) / (x * x - 1.0);
            double dx = p1 / dp;
            x -= dx;
            if (fabs(dx) < 1e-15) break;
        }
        double yy = x;
        double P[LMAX + 1][LMAX + 1] = {};
        P[0][0] = 1.0;
        double somx2 = sqrt(fmax(1.0 - yy * yy, 0.0));
        for (int m = 1; m <= LMAX; ++m) P[m][m] = -(2.0 * m - 1.0) * somx2 * P[m - 1][m - 1];
        for (int m = 0; m < LMAX; ++m)  P[m + 1][m] = (2.0 * m + 1.0) * yy * P[m][m];
        for (int m = 0; m <= LMAX; ++m)
            for (int l = m + 2; l <= LMAX; ++l)
                P[l][m] = ((2.0 * l - 1.0) * yy * P[l - 1][m] - (l + m - 1.0) * P[l - 2][m]) / (double)(l - m);
        for (int l = 0; l <= LMAX; ++l) {
            for (int m = 0; m <= l; ++m) {
                double fr = 1.0;                       // (l-m)!/(l+m)!
                for (int k = l - m + 1; k <= l + m; ++k) fr /= (double)k;
                double N = sqrt((2.0 * l + 1.0) / FOURPI * fr);
                double w = N * P[l][m];
                if (m > 0) w *= 1.4142135623730951;
                g_tab[i * NW21 + l * (l + 1) / 2 + m] = (float)w;
            }
        }
    }
    g_tab_ready = true;
}

// ---------------------------------------------------------------------------
// K1: per-graph small path. One block per graph, 256 threads. (unchanged)
__global__ __launch_bounds__(256)
void k_small(const float* __restrict__ ne, const float* __restrict__ sp,
             const float* __restrict__ wrad, const float* __restrict__ wm1,
             const float* __restrict__ wm2,
             const float* __restrict__ wa0, const float* __restrict__ wa1,
             const float* __restrict__ wa2, const float* __restrict__ wa3,
             const float* __restrict__ wa4, const float* __restrict__ wa5,
             const int* __restrict__ focus, const int* __restrict__ tspec,
             float* __restrict__ out0, float* __restrict__ out3,
             float* __restrict__ ang_ws, float* __restrict__ rad_ws)
{
    __shared__ float s0[MUL];
    __shared__ float rr[NRAD];
    __shared__ float hh[MUL];
    __shared__ float rl[NRAD];
    __shared__ float sang[NCH * SH_DIM];

    const int g = blockIdx.x;
    const int tid = threadIdx.x;
    const int fi = focus[g];
    const int ts = tspec[g];
    const float rs128 = 0.08838834764831845f;   // 1/sqrt(128)
    const float rs64  = 0.125f;                 // 1/sqrt(64)

    if (tid < MUL) s0[tid] = ne[(size_t)fi * EMB_DIM + tid] * sp[ts * NIRR + tid];
    __syncthreads();

    if (tid < NRAD) {
        float acc = 0.f;
        for (int k = 0; k < MUL; ++k) acc += s0[k] * wrad[k * NRAD + tid];
        rr[tid] = acc * rs128;
    }
    __syncthreads();

    if (tid < MUL) {
        float acc = 0.f;
        for (int j = 0; j < NRAD; ++j) acc += rr[j] * wm1[j * MUL + tid];
        float x = acc * rs64;
        hh[tid] = fmaxf(x, 0.f) + log1pf(expf(-fabsf(x)));   // stable softplus
    }
    __syncthreads();

    if (tid < NRAD) {
        float acc = 0.f;
        for (int k = 0; k < MUL; ++k) acc += hh[k] * wm2[k * NRAD + tid];
        float v = acc * rs128;
        rl[tid] = v;
        out3[g * NRAD + tid] = v;
        rad_ws[g * NRAD + tid] = v;
    }

    // angular coefficients: ang[c][l*l + j] = rs128 * sum_k ne_blk[k][j]*spec[k]*W_l[k][c]
    const float* WA[6] = {wa0, wa1, wa2, wa3, wa4, wa5};
    for (int t = tid; t < NCH * SH_DIM; t += blockDim.x) {
        int c = t / SH_DIM, kk = t % SH_DIM;
        int l = 0;
        while ((l + 1) * (l + 1) <= kk) ++l;
        int j = kk - l * l;
        int d = 2 * l + 1;
        const float* w  = WA[l];
        const float* nb = ne + (size_t)fi * EMB_DIM + MUL * l * l + j;
        const float* sb = sp + ts * NIRR + MUL * l;
        float acc = 0.f;
        for (int k = 0; k < MUL; ++k) acc += nb[k * d] * sb[k] * w[k * NCH + c];
        float v = acc * rs128;
        sang[t] = v;
        ang_ws[g * (NCH * SH_DIM) + t] = v;
    }
    __syncthreads();

    // log_position_coeffs[g,c,r,kk] = ang[c,kk] + (kk==0 ? rad[r] : 0)
    for (int t = tid; t < NCH * NRAD * SH_DIM; t += blockDim.x) {
        int kk = t % SH_DIM;
        int r  = (t / SH_DIM) % NRAD;
        int c  = t / (SH_DIM * NRAD);
        float v = sang[c * SH_DIM + kk];
        if (kk == 0) v += rl[r];
        out0[(size_t)g * (NCH * NRAD * SH_DIM) + t] = v;
    }
}

// ---------------------------------------------------------------------------
// K2 (fused): per (beta, g) block:
//   angular_logits[g,beta,a] = logsumexp_c( Fourier synthesis of ang coeffs )
//   position_logits[g,r,beta,a] = angular_logits[g,beta,a] + rad[g,r]*B00
// Weights come from the host-precomputed table (no fp64 on device).
__global__ __launch_bounds__(256)
void k_fused(const float* __restrict__ tab, const float* __restrict__ ang_ws,
             const float* __restrict__ rad_ws,
             float* __restrict__ out2, float* __restrict__ out1)
{
    __shared__ float sW[NW21];
    __shared__ float sAng[NCH * SH_DIM];
    __shared__ float sF[NCH][11];
    __shared__ float sRC[NRAD];

    const int beta = blockIdx.x;
    const int g    = blockIdx.y;
    const int tid  = threadIdx.x;

    if (tid < NW21) sW[tid] = tab[beta * NW21 + tid];
    if (tid >= 64 && tid < 64 + NRAD)
        sRC[tid - 64] = rad_ws[g * NRAD + (tid - 64)] * 0.28209479177387814f;  // B00 = 1/sqrt(4pi)
    for (int t = tid; t < NCH * SH_DIM; t += 256)
        sAng[t] = ang_ws[g * (NCH * SH_DIM) + t];
    __syncthreads();

    // Fourier coefficients per channel: a0 | a_m (cos) | s_m (sin)
    if (tid < NCH * 11) {
        int c = tid / 11, j = tid % 11;
        float acc = 0.f;
        if (j == 0) {
            for (int l = 0; l <= LMAX; ++l)
                acc += sAng[c * SH_DIM + l * l + l] * sW[l * (l + 1) / 2];
        } else if (j <= 5) {
            int m = j;
            for (int l = m; l <= LMAX; ++l)
                acc += sAng[c * SH_DIM + l * l + l + m] * sW[l * (l + 1) / 2 + m];
        } else {
            int m = j - 5;
            for (int l = m; l <= LMAX; ++l)
                acc += sAng[c * SH_DIM + l * l + l - m] * sW[l * (l + 1) / 2 + m];
        }
        sF[c][j] = acc;
    }
    __syncthreads();

    const float dalpha = 6.283185307179586f / 359.0f;
    for (int a = tid; a < RALPHA; a += 256) {
        float alpha = dalpha * (float)a;
        float s1, c1;
        __sincosf(alpha, &s1, &c1);
        float t0 = sF[0][0], t1 = sF[1][0], t2 = sF[2][0], t3 = sF[3][0];
        float cm = c1, sm = s1;
        for (int m = 1; m <= 5; ++m) {
            t0 += sF[0][m] * cm + sF[0][5 + m] * sm;
            t1 += sF[1][m] * cm + sF[1][5 + m] * sm;
            t2 += sF[2][m] * cm + sF[2][5 + m] * sm;
            t3 += sF[3][m] * cm + sF[3][5 + m] * sm;
            float cn = cm * c1 - sm * s1;
            float sn = sm * c1 + cm * s1;
            cm = cn; sm = sn;
        }
        float mx = fmaxf(fmaxf(t0, t1), fmaxf(t2, t3));
        float s = expf(t0 - mx) + expf(t1 - mx) + expf(t2 - mx) + expf(t3 - mx);
        float L = mx + logf(s);

        out2[(size_t)g * GRID_BA + beta * RALPHA + a] = L;

        float* p = out1 + (size_t)g * NRAD * GRID_BA + (size_t)(beta * RALPHA + a);
        #pragma unroll 8
        for (int r = 0; r < NRAD; ++r)
            p[(size_t)r * GRID_BA] = L + sRC[r];
    }
}

// ---------------------------------------------------------------------------
extern "C" void kernel_launch(void* const* d_in, const int* in_sizes, int n_in,
                              void* d_out, int out_size, void* d_ws, size_t ws_size,
                              hipStream_t stream) {
    host_init_tab();   // pure CPU, runs once

    const float* ne   = (const float*)d_in[0];
    const float* sp   = (const float*)d_in[1];
    const float* wrad = (const float*)d_in[2];
    const float* wm1  = (const float*)d_in[3];
    const float* wm2  = (const float*)d_in[4];
    const float* wa0  = (const float*)d_in[5];
    const float* wa1  = (const float*)d_in[6];
    const float* wa2  = (const float*)d_in[7];
    const float* wa3  = (const float*)d_in[8];
    const float* wa4  = (const float*)d_in[9];
    const float* wa5  = (const float*)d_in[10];
    const int* focus  = (const int*)d_in[11];
    const int* tspec  = (const int*)d_in[12];

    float* out  = (float*)d_out;
    float* out0 = out + OUT0_OFF;
    float* out1 = out + OUT1_OFF;
    float* out2 = out + OUT2_OFF;
    float* out3 = out + OUT3_OFF;

    float* tab    = (float*)((char*)d_ws + WS_TAB_OFF);
    float* ang_ws = (float*)((char*)d_ws + WS_ANG_OFF);
    float* rad_ws = (float*)((char*)d_ws + WS_RAD_OFF);

    hipMemcpyAsync(tab, g_tab, sizeof(g_tab), hipMemcpyHostToDevice, stream);

    hipLaunchKernelGGL(k_small, dim3(NGRAPH), dim3(256), 0, stream,
                       ne, sp, wrad, wm1, wm2, wa0, wa1, wa2, wa3, wa4, wa5,
                       focus, tspec, out0, out3, ang_ws, rad_ws);
    hipLaunchKernelGGL(k_fused, dim3(RBETA, NGRAPH), dim3(256), 0, stream,
                       tab, ang_ws, rad_ws, out2, out1);
}

// Round 2
// 335.048 us; speedup vs baseline: 1.1338x; 1.1338x over previous
//
#include <hip/hip_runtime.h>
#include <math.h>

#define LMAX   5
#define MUL    128
#define NCH    4
#define NRAD   64
#define RBETA  180
#define RALPHA 359
#define NGRAPH 16
#define SH_DIM 36
#define EMB_DIM 4608
#define NIRR   768

#define GRID_BA (RBETA * RALPHA)          // 64620
#define N_F4    (GRID_BA / 4)             // 16155, exact
#define NW21    21                        // (LMAX+1)(LMAX+2)/2 packed (l,m) weights

// out layout (floats): [0] coeffs 147456 | [1] pos 66170880 | [2] ang 1033920 | [3] rad 1024
#define OUT0_OFF 0
#define OUT1_OFF 147456
#define OUT2_OFF (147456 + 66170880)
#define OUT3_OFF (147456 + 66170880 + 1033920)

// ws layout (bytes):
//   float tab[180*21]  @ 0      (15120 B, padded to 15360)
//   float ang[16][144] @ 15360  (9216 B)
//   float rad[16][64]  @ 24576  (4096 B)
#define WS_TAB_OFF 0
#define WS_ANG_OFF 15360
#define WS_RAD_OFF 24576

// ---------------------------------------------------------------------------
// K1: per-graph small path (blocks 0..15) + SH weight-table init (block 16).
// Table init is fully parallel: thread i owns Gauss-Legendre node i (Newton on
// P_180 in fp64, independent per node) and emits its 21 packed weights
//   tab[i][l(l+1)/2+m] = (m==0?1:sqrt2) * N_lm * P_lm(y_i)
__global__ __launch_bounds__(256)
void k_small(const float* __restrict__ ne, const float* __restrict__ sp,
             const float* __restrict__ wrad, const float* __restrict__ wm1,
             const float* __restrict__ wm2,
             const float* __restrict__ wa0, const float* __restrict__ wa1,
             const float* __restrict__ wa2, const float* __restrict__ wa3,
             const float* __restrict__ wa4, const float* __restrict__ wa5,
             const int* __restrict__ focus, const int* __restrict__ tspec,
             float* __restrict__ out0, float* __restrict__ out3,
             float* __restrict__ ang_ws, float* __restrict__ rad_ws,
             float* __restrict__ tab)
{
    const int tid = threadIdx.x;

    if (blockIdx.x == NGRAPH) {
        // ---- table-init block ----
        __shared__ double rcp[RBETA];     // 1/(k+1)
        for (int k = tid; k < RBETA; k += 256) rcp[k] = 1.0 / (double)(k + 1);
        __syncthreads();
        const int i = tid;
        if (i >= RBETA) return;
        const double PI = 3.14159265358979323846;
        double x = -cos(PI * (i + 0.75) / (RBETA + 0.5));   // ascending node guess
        for (int it = 0; it < 6; ++it) {
            double p0 = 1.0, p1 = x;
            for (int k = 1; k < RBETA; ++k) {
                double p2 = ((2.0 * k + 1.0) * x * p1 - (double)k * p0) * rcp[k];
                p0 = p1; p1 = p2;
            }
            double dp = RBETA * (x * p1 - p0) / (x * x - 1.0);
            x -= p1 / dp;
        }
        // associated Legendre + normalization at this node
        double P[LMAX + 1][LMAX + 1];
        P[0][0] = 1.0;
        double somx2 = sqrt(fmax(1.0 - x * x, 0.0));
        for (int m = 1; m <= LMAX; ++m) P[m][m] = -(2.0 * m - 1.0) * somx2 * P[m - 1][m - 1];
        for (int m = 0; m < LMAX; ++m)  P[m + 1][m] = (2.0 * m + 1.0) * x * P[m][m];
        for (int m = 0; m <= LMAX; ++m)
            for (int l = m + 2; l <= LMAX; ++l)
                P[l][m] = ((2.0 * l - 1.0) * x * P[l - 1][m] - (l + m - 1.0) * P[l - 2][m]) / (double)(l - m);
        const double FOURPI = 12.566370614359172;
        for (int l = 0; l <= LMAX; ++l) {
            for (int m = 0; m <= l; ++m) {
                double fr = 1.0;                       // (l-m)!/(l+m)!
                for (int k = l - m + 1; k <= l + m; ++k) fr /= (double)k;
                double N = sqrt((2.0 * l + 1.0) / FOURPI * fr);
                double w = N * P[l][m];
                if (m > 0) w *= 1.4142135623730951;
                tab[i * NW21 + l * (l + 1) / 2 + m] = (float)w;
            }
        }
        return;
    }

    // ---- per-graph small path ----
    __shared__ float s0[MUL];
    __shared__ float rr[NRAD];
    __shared__ float hh[MUL];
    __shared__ float rl[NRAD];
    __shared__ float sang[NCH * SH_DIM];

    const int g = blockIdx.x;
    const int fi = focus[g];
    const int ts = tspec[g];
    const float rs128 = 0.08838834764831845f;   // 1/sqrt(128)
    const float rs64  = 0.125f;                 // 1/sqrt(64)

    if (tid < MUL) s0[tid] = ne[(size_t)fi * EMB_DIM + tid] * sp[ts * NIRR + tid];
    __syncthreads();

    if (tid < NRAD) {
        float acc = 0.f;
        for (int k = 0; k < MUL; ++k) acc += s0[k] * wrad[k * NRAD + tid];
        rr[tid] = acc * rs128;
    }
    __syncthreads();

    if (tid < MUL) {
        float acc = 0.f;
        for (int j = 0; j < NRAD; ++j) acc += rr[j] * wm1[j * MUL + tid];
        float x = acc * rs64;
        hh[tid] = fmaxf(x, 0.f) + log1pf(expf(-fabsf(x)));   // stable softplus
    }
    __syncthreads();

    if (tid < NRAD) {
        float acc = 0.f;
        for (int k = 0; k < MUL; ++k) acc += hh[k] * wm2[k * NRAD + tid];
        float v = acc * rs128;
        rl[tid] = v;
        out3[g * NRAD + tid] = v;
        rad_ws[g * NRAD + tid] = v;
    }

    // angular coefficients: ang[c][l*l + j] = rs128 * sum_k ne_blk[k][j]*spec[k]*W_l[k][c]
    const float* WA[6] = {wa0, wa1, wa2, wa3, wa4, wa5};
    for (int t = tid; t < NCH * SH_DIM; t += blockDim.x) {
        int c = t / SH_DIM, kk = t % SH_DIM;
        int l = 0;
        while ((l + 1) * (l + 1) <= kk) ++l;
        int j = kk - l * l;
        int d = 2 * l + 1;
        const float* w  = WA[l];
        const float* nb = ne + (size_t)fi * EMB_DIM + MUL * l * l + j;
        const float* sb = sp + ts * NIRR + MUL * l;
        float acc = 0.f;
        for (int k = 0; k < MUL; ++k) acc += nb[k * d] * sb[k] * w[k * NCH + c];
        float v = acc * rs128;
        sang[t] = v;
        ang_ws[g * (NCH * SH_DIM) + t] = v;
    }
    __syncthreads();

    // log_position_coeffs[g,c,r,kk] = ang[c,kk] + (kk==0 ? rad[r] : 0)
    for (int t = tid; t < NCH * NRAD * SH_DIM; t += blockDim.x) {
        int kk = t % SH_DIM;
        int r  = (t / SH_DIM) % NRAD;
        int c  = t / (SH_DIM * NRAD);
        float v = sang[c * SH_DIM + kk];
        if (kk == 0) v += rl[r];
        out0[(size_t)g * (NCH * NRAD * SH_DIM) + t] = v;
    }
}

// ---------------------------------------------------------------------------
// K2: angular_logits[g,beta,a] = logsumexp_c( Fourier synthesis of ang coeffs )
// Per (beta,g) block; SH weights read from the device-precomputed table.
__global__ __launch_bounds__(256)
void k_angular(const float* __restrict__ tab, const float* __restrict__ ang_ws,
               float* __restrict__ out2)
{
    __shared__ float sW[NW21];
    __shared__ float sAng[NCH * SH_DIM];
    __shared__ float sF[NCH][11];

    const int beta = blockIdx.x;
    const int g    = blockIdx.y;
    const int tid  = threadIdx.x;

    if (tid < NW21) sW[tid] = tab[beta * NW21 + tid];
    for (int t = tid; t < NCH * SH_DIM; t += 256)
        sAng[t] = ang_ws[g * (NCH * SH_DIM) + t];
    __syncthreads();

    // Fourier coefficients per channel: a0 | a_m (cos) | s_m (sin)
    if (tid < NCH * 11) {
        int c = tid / 11, j = tid % 11;
        float acc = 0.f;
        if (j == 0) {
            for (int l = 0; l <= LMAX; ++l)
                acc += sAng[c * SH_DIM + l * l + l] * sW[l * (l + 1) / 2];
        } else if (j <= 5) {
            int m = j;
            for (int l = m; l <= LMAX; ++l)
                acc += sAng[c * SH_DIM + l * l + l + m] * sW[l * (l + 1) / 2 + m];
        } else {
            int m = j - 5;
            for (int l = m; l <= LMAX; ++l)
                acc += sAng[c * SH_DIM + l * l + l - m] * sW[l * (l + 1) / 2 + m];
        }
        sF[c][j] = acc;
    }
    __syncthreads();

    const float dalpha = 6.283185307179586f / 359.0f;
    for (int a = tid; a < RALPHA; a += 256) {
        float alpha = dalpha * (float)a;
        float s1, c1;
        __sincosf(alpha, &s1, &c1);
        float t0 = sF[0][0], t1 = sF[1][0], t2 = sF[2][0], t3 = sF[3][0];
        float cm = c1, sm = s1;
        for (int m = 1; m <= 5; ++m) {
            t0 += sF[0][m] * cm + sF[0][5 + m] * sm;
            t1 += sF[1][m] * cm + sF[1][5 + m] * sm;
            t2 += sF[2][m] * cm + sF[2][5 + m] * sm;
            t3 += sF[3][m] * cm + sF[3][5 + m] * sm;
            float cn = cm * c1 - sm * s1;
            float sn = sm * c1 + cm * s1;
            cm = cn; sm = sn;
        }
        float mx = fmaxf(fmaxf(t0, t1), fmaxf(t2, t3));
        float s = expf(t0 - mx) + expf(t1 - mx) + expf(t2 - mx) + expf(t3 - mx);
        out2[(size_t)g * GRID_BA + beta * RALPHA + a] = mx + logf(s);
    }
}

// ---------------------------------------------------------------------------
// K3: position_logits[g,r,:,:] = angular_logits[g,:,:] + radial[g,r]*B00
// Pure float4 streaming broadcast-add; reads of out2 hit L2 (258 KB/graph).
// B00 = 1/sqrt(4*pi).
__global__ __launch_bounds__(256)
void k_pos(const float* __restrict__ out2, const float* __restrict__ rad_ws,
           float* __restrict__ out1)
{
    const int g = blockIdx.z;
    const int r = blockIdx.y;
    const int i = blockIdx.x * 256 + threadIdx.x;     // float4 index
    if (i >= N_F4) return;
    const float rc = rad_ws[g * NRAD + r] * 0.28209479177387814f;
    const float4* src = (const float4*)(out2 + (size_t)g * GRID_BA);
    float4 v = src[i];
    v.x += rc; v.y += rc; v.z += rc; v.w += rc;
    float4* dst = (float4*)(out1 + ((size_t)(g * NRAD + r)) * GRID_BA);
    dst[i] = v;
}

// ---------------------------------------------------------------------------
extern "C" void kernel_launch(void* const* d_in, const int* in_sizes, int n_in,
                              void* d_out, int out_size, void* d_ws, size_t ws_size,
                              hipStream_t stream) {
    const float* ne   = (const float*)d_in[0];
    const float* sp   = (const float*)d_in[1];
    const float* wrad = (const float*)d_in[2];
    const float* wm1  = (const float*)d_in[3];
    const float* wm2  = (const float*)d_in[4];
    const float* wa0  = (const float*)d_in[5];
    const float* wa1  = (const float*)d_in[6];
    const float* wa2  = (const float*)d_in[7];
    const float* wa3  = (const float*)d_in[8];
    const float* wa4  = (const float*)d_in[9];
    const float* wa5  = (const float*)d_in[10];
    const int* focus  = (const int*)d_in[11];
    const int* tspec  = (const int*)d_in[12];

    float* out  = (float*)d_out;
    float* out0 = out + OUT0_OFF;
    float* out1 = out + OUT1_OFF;
    float* out2 = out + OUT2_OFF;
    float* out3 = out + OUT3_OFF;

    float* tab    = (float*)((char*)d_ws + WS_TAB_OFF);
    float* ang_ws = (float*)((char*)d_ws + WS_ANG_OFF);
    float* rad_ws = (float*)((char*)d_ws + WS_RAD_OFF);

    // blocks 0..15: per-graph path; block 16: parallel SH-table init
    hipLaunchKernelGGL(k_small, dim3(NGRAPH + 1), dim3(256), 0, stream,
                       ne, sp, wrad, wm1, wm2, wa0, wa1, wa2, wa3, wa4, wa5,
                       focus, tspec, out0, out3, ang_ws, rad_ws, tab);
    hipLaunchKernelGGL(k_angular, dim3(RBETA, NGRAPH), dim3(256), 0, stream,
                       tab, ang_ws, out2);
    hipLaunchKernelGGL(k_pos, dim3((N_F4 + 255) / 256, NRAD, NGRAPH), dim3(256), 0, stream,
                       out2, rad_ws, out1);
}